// Round 12
// baseline (164.162 us; speedup 1.0000x reference)
//
#include <hip/hip_runtime.h>
#include <hip/hip_bf16.h>
#include <math.h>

typedef unsigned short u16;
typedef __attribute__((ext_vector_type(8))) short bf16x8;
typedef __attribute__((ext_vector_type(4))) float f32x4;

constexpr int D_ = 1024;
constexpr int H_ = 1365;
constexpr int E_ = 7;
constexpr int NTOK = 2048;
constexpr int HP = 1408;          // H padded to multiple of 64
constexpr int NE = 8;             // 7 routed + 1 shared
constexpr int SHARED_BASE = 4096;
constexpr int SLOTS = 6144;

#define CI_COUNT 0
#define CI_OFF   8

constexpr size_t WS_CTRL = 0;
constexpr size_t WS_TIDX = 256;
constexpr size_t WS_TW   = WS_TIDX + (size_t)NTOK*2*4;
constexpr size_t WS_PROB = WS_TW   + (size_t)NTOK*2*4;
constexpr size_t WS_LSE2 = WS_PROB + (size_t)NTOK*8*4;
constexpr size_t WS_STOK = WS_LSE2 + (size_t)NTOK*4;
constexpr size_t WS_SW   = WS_STOK + (size_t)SLOTS*4;
constexpr size_t WS_B1   = WS_SW   + (size_t)SLOTS*4;
constexpr size_t WS_B2   = WS_B1   + (size_t)NE*H_*4;
constexpr size_t WS_XB   = ((WS_B2 + (size_t)NE*D_*4) + 255) & ~(size_t)255;
constexpr size_t WS_W1B  = WS_XB  + (size_t)NTOK*D_*2;
constexpr size_t WS_W2B  = WS_W1B + (size_t)NE*H_*D_*2;
constexpr size_t WS_HEB  = WS_W2B + (size_t)NE*D_*HP*2;

__device__ __forceinline__ u16 f2bf(float f) {
    __hip_bfloat16 h = __float2bfloat16(f);
    return __builtin_bit_cast(u16, h);
}

__device__ __forceinline__ void gload_lds16(const u16* g, u16* l) {
    __builtin_amdgcn_global_load_lds(
        (const __attribute__((address_space(1))) void*)g,
        (__attribute__((address_space(3))) void*)l, 16, 0, 0);
}

__device__ __forceinline__ uint4 pack8(float4 a, float4 b) {
    union { u16 h[8]; uint4 v; } u;
    u.h[0]=f2bf(a.x); u.h[1]=f2bf(a.y); u.h[2]=f2bf(a.z); u.h[3]=f2bf(a.w);
    u.h[4]=f2bf(b.x); u.h[5]=f2bf(b.y); u.h[6]=f2bf(b.z); u.h[7]=f2bf(b.w);
    return u.v;
}

// tanh-form GELU (|err| ~3e-3, below bf16 quantization of He)
__device__ __forceinline__ float fast_gelu(float v) {
    float u = 0.7978845608f * v * (1.f + 0.044715f * v * v);
    float e = __expf(2.f * u);
    float t = 1.f - 2.f / (e + 1.f);
    return 0.5f * v * (1.f + t);
}

// ===== GEMM core: 128x128 block, BK=64, SINGLE-buffer 32KB LDS, 512 thr / 8 waves =====
// 16x16x32 fragments (measured 0-conflict read pattern), 4 blocks/CU = 32 waves/CU.
#define BM 128
#define BN 128
#define KSTEP 64
#define ATILE (BM*KSTEP)    // 8192 elems = 16 KiB

#define MFMA16(a,b,c) __builtin_amdgcn_mfma_f32_16x16x32_bf16(a, b, c, 0, 0, 0)

template<bool USE_STOK>
__device__ __forceinline__ void gemm1_body(u16* As, u16* Bs,
    const u16* xb, const u16* w1e, const float* b1e,
    const int* stok, int offset, int m0, int valid, int nt,
    u16* heb)
{
    int t = threadIdx.x, wid = t >> 6, lane = t & 63;
    int rl = lane >> 3, cl = lane & 7;
    int sg = cl ^ rl;                    // pre-swizzled 16B-chunk (involution on row&7)

    const u16* aP[2]; const u16* bP[2]; int dOff[2];
    #pragma unroll
    for (int c = 0; c < 2; c++) {
        int row = wid*16 + c*8 + rl;
        int ar = min(row, valid-1);
        int tok = USE_STOK ? stok[offset + m0 + ar] : (m0 + ar);
        aP[c] = xb + (size_t)tok*D_ + sg*8;
        int jg = min(nt*BN + row, H_-1);
        bP[c] = w1e + (size_t)jg*D_ + sg*8;
        dOff[c] = (wid*16 + c*8)*KSTEP;
    }

    int wm = (wid >> 2)*64, wn = (wid & 3)*32;
    int frow = lane & 15, kgrp = lane >> 4, swz = frow & 7;
    f32x4 acc[4][2] = {};

    constexpr int nIter = D_/KSTEP;      // 16
    for (int tt = 0; tt < nIter; ++tt) {
        __syncthreads();                 // previous compute done before overwrite
        int ko = tt*KSTEP;
        #pragma unroll
        for (int c = 0; c < 2; c++) {
            gload_lds16(aP[c]+ko, As + dOff[c]);
            gload_lds16(bP[c]+ko, Bs + dOff[c]);
        }
        __syncthreads();                 // drains vmcnt(0): tile ready
        __builtin_amdgcn_s_setprio(1);
        #pragma unroll
        for (int s = 0; s < 2; s++) {
            int cc = ((s*4 + kgrp) ^ swz) * 8;
            bf16x8 af[4], bf[2];
            #pragma unroll
            for (int mf = 0; mf < 4; mf++)
                af[mf] = *(const bf16x8*)&As[(wm + mf*16 + frow)*KSTEP + cc];
            #pragma unroll
            for (int nf = 0; nf < 2; nf++)
                bf[nf] = *(const bf16x8*)&Bs[(wn + nf*16 + frow)*KSTEP + cc];
            #pragma unroll
            for (int mf = 0; mf < 4; mf++)
                #pragma unroll
                for (int nf = 0; nf < 2; nf++)
                    acc[mf][nf] = MFMA16(af[mf], bf[nf], acc[mf][nf]);
        }
        __builtin_amdgcn_s_setprio(0);
    }

    int r4 = (lane >> 4)*4, cEl = lane & 15;
    #pragma unroll
    for (int nf = 0; nf < 2; nf++) {
        int gcol = nt*BN + wn + nf*16 + cEl;
        bool cok = gcol < H_;
        float bias = cok ? b1e[gcol] : 0.f;
        #pragma unroll
        for (int mf = 0; mf < 4; mf++) {
            #pragma unroll
            for (int r = 0; r < 4; r++) {
                int row = wm + mf*16 + r4 + r;
                if (row < valid) {
                    float v = 0.f;
                    if (cok) v = fast_gelu(acc[mf][nf][r] + bias);
                    heb[(size_t)(offset + m0 + row)*HP + gcol] = f2bf(v);
                }
            }
        }
    }
}

// out += w * (He @ W2e^T + b2e), always atomicAdd (out pre-zeroed; shared uses w=1)
__device__ __forceinline__ void gemm2_body(u16* As, u16* Bs,
    const u16* heb, const u16* w2e, const float* b2e, const float* sw,
    int offset, int m0, int valid, int nt, float* out, const int* stok)
{
    int t = threadIdx.x, wid = t >> 6, lane = t & 63;
    int rl = lane >> 3, cl = lane & 7;
    int sg = cl ^ rl;

    const u16* aP[2]; const u16* bP[2]; int dOff[2];
    #pragma unroll
    for (int c = 0; c < 2; c++) {
        int row = wid*16 + c*8 + rl;
        int ar = min(row, valid-1);
        aP[c] = heb + (size_t)(offset + m0 + ar)*HP + sg*8;
        int jg = nt*BN + row;             // < 1024 always
        bP[c] = w2e + (size_t)jg*HP + sg*8;
        dOff[c] = (wid*16 + c*8)*KSTEP;
    }

    int wm = (wid >> 2)*64, wn = (wid & 3)*32;
    int frow = lane & 15, kgrp = lane >> 4, swz = frow & 7;
    f32x4 acc[4][2] = {};

    constexpr int nIter = HP/KSTEP;      // 22
    for (int tt = 0; tt < nIter; ++tt) {
        __syncthreads();
        int ko = tt*KSTEP;
        #pragma unroll
        for (int c = 0; c < 2; c++) {
            gload_lds16(aP[c]+ko, As + dOff[c]);
            gload_lds16(bP[c]+ko, Bs + dOff[c]);
        }
        __syncthreads();
        __builtin_amdgcn_s_setprio(1);
        #pragma unroll
        for (int s = 0; s < 2; s++) {
            int cc = ((s*4 + kgrp) ^ swz) * 8;
            bf16x8 af[4], bf[2];
            #pragma unroll
            for (int mf = 0; mf < 4; mf++)
                af[mf] = *(const bf16x8*)&As[(wm + mf*16 + frow)*KSTEP + cc];
            #pragma unroll
            for (int nf = 0; nf < 2; nf++)
                bf[nf] = *(const bf16x8*)&Bs[(wn + nf*16 + frow)*KSTEP + cc];
            #pragma unroll
            for (int mf = 0; mf < 4; mf++)
                #pragma unroll
                for (int nf = 0; nf < 2; nf++)
                    acc[mf][nf] = MFMA16(af[mf], bf[nf], acc[mf][nf]);
        }
        __builtin_amdgcn_s_setprio(0);
    }

    int r4 = (lane >> 4)*4, cEl = lane & 15;
    #pragma unroll
    for (int nf = 0; nf < 2; nf++) {
        int gcol = nt*BN + wn + nf*16 + cEl;
        float bias = b2e[gcol];
        #pragma unroll
        for (int mf = 0; mf < 4; mf++) {
            #pragma unroll
            for (int r = 0; r < 4; r++) {
                int row = wm + mf*16 + r4 + r;
                if (row < valid) {
                    int slot = offset + m0 + row;
                    atomicAdd(out + (size_t)stok[slot]*D_ + gcol,
                              sw[slot]*(acc[mf][nf][r] + bias));
                }
            }
        }
    }
}

// ================= finalize (512 threads): counts, offsets, losses, scatter =================
__device__ void finalize_body(char* big, char* small,
    const int* tidx, const float* tw, const float* probs, const float* lse2,
    int* ci, int* stok, float* sw, float* out)
{
    int*   lt   = (int*)big;                // 4096 ints (16 KiB)
    float* psum = (float*)small;
    float* lsum = (float*)(small + 32);
    int*   cntS = (int*)(small + 64);
    int*   offS = (int*)(small + 96);
    int t = threadIdx.x;
    if (t < 8) { psum[t] = 0.f; cntS[t] = 0; }
    if (t == 0) *lsum = 0.f;
    for (int i = t; i < NTOK*2; i += 512) lt[i] = tidx[i];
    __syncthreads();
    float lp[E_] = {}; float ll = 0.f;
    for (int n = t; n < NTOK; n += 512) {
        #pragma unroll
        for (int e = 0; e < E_; e++) lp[e] += probs[n*8+e];
        ll += lse2[n];
    }
    #pragma unroll
    for (int e = 0; e < E_; e++) atomicAdd(&psum[e], lp[e]);
    atomicAdd(lsum, ll);
    int wid = t >> 6, lane = t & 63;
    if (wid < 7) {
        int c = 0;
        for (int i = lane; i < NTOK*2; i += 64) c += (lt[i] == wid) ? 1 : 0;
        #pragma unroll
        for (int m = 32; m >= 1; m >>= 1) c += __shfl_xor(c, m);
        if (lane == 0) cntS[wid] = c;
    } else {
        for (int n = lane; n < NTOK; n += 64) {
            stok[SHARED_BASE+n] = n; sw[SHARED_BASE+n] = 1.f;
        }
    }
    __syncthreads();
    if (t == 0) {
        int o = 0;
        for (int e = 0; e < E_; e++) { offS[e] = o; o += cntS[e]; }
        offS[7] = SHARED_BASE; cntS[7] = NTOK;
        float la = 0.f;
        for (int e = 0; e < E_; e++)
            la += ((float)cntS[e] / (float)(NTOK*2)) * (psum[e] / (float)NTOK);
        out[(size_t)NTOK*D_]     = 0.01f * 7.f * la;
        out[(size_t)NTOK*D_ + 1] = 0.001f * (*lsum) / (float)NTOK;
        #pragma unroll
        for (int e = 0; e < 8; e++) { ci[CI_COUNT+e] = cntS[e]; ci[CI_OFF+e] = offS[e]; }
    }
    __syncthreads();
    if (wid < 7) {
        int base = offS[wid], run = 0;
        for (int c0 = 0; c0 < NTOK*2; c0 += 64) {
            bool m = (lt[c0 + lane] == wid);
            unsigned long long bal = __ballot(m);
            int pre = __popcll(bal & ((1ull << lane) - 1ull));
            if (m) {
                int i = c0 + lane;
                int s = base + run + pre;
                stok[s] = i >> 1; sw[s] = tw[i];
            }
            run += __popcll(bal);
        }
    }
}

// ==== k1: router (0..511) || W1+b1 convert, 4-deep ILP (512..2047) — NO LDS ====
__global__ void prep_kernel(
    const float* __restrict__ x, const float* __restrict__ Wg,
    const float* __restrict__ W1, const float* __restrict__ Ws1,
    const float* __restrict__ b1, const float* __restrict__ bs1,
    int* __restrict__ tidx, float* __restrict__ tw,
    float* __restrict__ probs, float* __restrict__ lse2,
    u16* __restrict__ xb, u16* __restrict__ w1b, float* __restrict__ b1all)
{
    int b = blockIdx.x;
    if (b < 512) {
        int wid = threadIdx.x >> 6, lane = threadIdx.x & 63;
        int n = b*4 + wid;
        float p[E_] = {};
        const float* xr = x + (size_t)n*D_;
        u16* xbr = xb + (size_t)n*D_;
        #pragma unroll
        for (int j = 0; j < 4; j++) {
            int d0 = lane*4 + j*256;
            float4 xv = *(const float4*)(xr + d0);
            ushort4 h;
            h.x = f2bf(xv.x); h.y = f2bf(xv.y); h.z = f2bf(xv.z); h.w = f2bf(xv.w);
            *(ushort4*)(xbr + d0) = h;
            #pragma unroll
            for (int e = 0; e < E_; e++) {
                float4 wv = *(const float4*)(Wg + e*D_ + d0);
                p[e] += xv.x*wv.x + xv.y*wv.y + xv.z*wv.z + xv.w*wv.w;
            }
        }
        #pragma unroll
        for (int e = 0; e < E_; e++) {
            float v = p[e];
            #pragma unroll
            for (int m = 32; m >= 1; m >>= 1) v += __shfl_xor(v, m);
            p[e] = v;
        }
        if (lane == 0) {
            float mx = p[0];
            #pragma unroll
            for (int e = 1; e < E_; e++) mx = fmaxf(mx, p[e]);
            float pr[E_], sum = 0.f;
            #pragma unroll
            for (int e = 0; e < E_; e++) { pr[e] = __expf(p[e]-mx); sum += pr[e]; }
            float lse = mx + logf(sum);
            int i0 = 0;
            #pragma unroll
            for (int e = 1; e < E_; e++) if (p[e] > p[i0]) i0 = e;
            int i1 = -1;
            #pragma unroll
            for (int e = 0; e < E_; e++) if (e != i0 && (i1 < 0 || p[e] > p[i1])) i1 = e;
            float g = expf(p[i1] - p[i0]);
            tidx[n*2] = i0; tidx[n*2+1] = i1;
            tw[n*2] = 1.f/(1.f+g); tw[n*2+1] = g/(1.f+g);
            float inv = 1.f/sum;
            #pragma unroll
            for (int e = 0; e < E_; e++) probs[n*8+e] = pr[e]*inv;
            lse2[n] = lse*lse;
        }
        return;
    }
    // ---- W1 convert: 4 strided uint4 groups per thread, all loads issued first ----
    const unsigned G1 = (unsigned)(NE*H_*D_/8);
    const unsigned NT = 1536u*256u;
    const unsigned W1FLAT = 7u*(unsigned)(H_*D_);
    unsigned tid = (unsigned)(b-512)*256u + threadIdx.x;
    unsigned i0 = tid, i1 = tid + NT, i2 = tid + 2u*NT, i3 = tid + 3u*NT;
    bool p3 = i3 < G1;
    float4 va0, vb0, va1, vb1, va2, vb2, va3, vb3;
    {
        const float* s0 = (i0*8u < W1FLAT) ? W1 + (size_t)i0*8u : Ws1 + ((size_t)i0*8u - W1FLAT);
        va0 = *(const float4*)s0; vb0 = *(const float4*)(s0+4);
        const float* s1 = (i1*8u < W1FLAT) ? W1 + (size_t)i1*8u : Ws1 + ((size_t)i1*8u - W1FLAT);
        va1 = *(const float4*)s1; vb1 = *(const float4*)(s1+4);
        const float* s2 = (i2*8u < W1FLAT) ? W1 + (size_t)i2*8u : Ws1 + ((size_t)i2*8u - W1FLAT);
        va2 = *(const float4*)s2; vb2 = *(const float4*)(s2+4);
        if (p3) {
            const float* s3 = (i3*8u < W1FLAT) ? W1 + (size_t)i3*8u : Ws1 + ((size_t)i3*8u - W1FLAT);
            va3 = *(const float4*)s3; vb3 = *(const float4*)(s3+4);
        }
    }
    ((uint4*)w1b)[i0] = pack8(va0, vb0);
    ((uint4*)w1b)[i1] = pack8(va1, vb1);
    ((uint4*)w1b)[i2] = pack8(va2, vb2);
    if (p3) ((uint4*)w1b)[i3] = pack8(va3, vb3);
    if (tid < 10920u) b1all[tid] = (tid < 9555u) ? b1[tid] : bs1[tid - 9555u];
}

// ===== k2: finalize (blk 0) || W2+b2 convert (1..512) — NO GEMM stragglers =====
__global__ __launch_bounds__(512, 8) void k2_kernel(
    const float* __restrict__ W2, const float* __restrict__ Ws2,
    const float* __restrict__ b2, const float* __restrict__ bs2,
    u16* __restrict__ w2b, float* __restrict__ b2all,
    const int* __restrict__ tidx, const float* __restrict__ tw,
    const float* __restrict__ probs, const float* __restrict__ lse2,
    int* __restrict__ ci, int* __restrict__ stok, float* __restrict__ sw,
    float* __restrict__ out)
{
    __shared__ char smA[16384];
    __shared__ char smB[128];
    int b = blockIdx.x;
    if (b == 0) {
        finalize_body(smA, smB, tidx, tw, probs, lse2, ci, stok, sw, out);
        return;
    }
    // ---- W2 convert: one wave per 2 destination rows, fully unrolled, pad folded in ----
    unsigned tid = (unsigned)(b-1)*512u + threadIdx.x;
    if (tid < 8192u) b2all[tid] = (tid < 7168u) ? b2[tid] : bs2[tid - 7168u];
    int lane = threadIdx.x & 63;
    int rw0 = (((b-1)*8) + (threadIdx.x >> 6)) * 2;   // 0..8190
    #pragma unroll
    for (int j = 0; j < 2; j++) {
        int rw = rw0 + j;
        int ec = rw >> 10, drow = rw & 1023;
        const float* src = (ec < 7) ? (W2 + ((size_t)ec*D_ + drow)*(size_t)H_)
                                    : (Ws2 + (size_t)drow*(size_t)H_);
        u16* dst = w2b + (size_t)rw*HP;
        #pragma unroll
        for (int h0 = 0; h0 < HP; h0 += 64) {
            int h = h0 + lane;
            float v = (h < H_) ? src[h] : 0.f;
            dst[h] = f2bf(v);
        }
    }
}

// ===== k3: ALL GEMM1 — routed (XCD-pinned, yb<176) || shared (yb>=176, spread) =====
__global__ __launch_bounds__(512, 8) void k3_kernel(
    const int* __restrict__ ci, const int* __restrict__ stok,
    const u16* __restrict__ xb, const u16* __restrict__ w1b,
    const float* __restrict__ b1all, u16* __restrict__ heb)
{
    __shared__ u16 As[ATILE];
    __shared__ u16 Bs[ATILE];
    int x = blockIdx.x, yb = blockIdx.y;
    if (yb < 176) {
        if (x == 7) return;
        int e = x, mt = yb/11, nt = yb - mt*11;
        int count = ci[CI_COUNT+e];
        int m0 = mt*BM;
        if (m0 >= count) return;
        gemm1_body<true>(As, Bs, xb, w1b + (size_t)e*H_*D_, b1all + e*H_,
                         stok, ci[CI_OFF+e], m0, min(BM, count-m0), nt, heb);
    } else {
        int idx = (yb - 176)*8 + x;       // 0..175 (22*8)
        int mt = idx/11, nt = idx - mt*11;
        gemm1_body<false>(As, Bs, xb, w1b + (size_t)7*H_*D_, b1all + 7*H_,
                          nullptr, SHARED_BASE, mt*BM, BM, nt, heb);
    }
}

// ===== k4: ALL GEMM2 — routed (XCD-pinned, yb<128) || shared (yb>=128), atomicAdd =====
__global__ __launch_bounds__(512, 8) void k4_kernel(
    const int* __restrict__ ci, const int* __restrict__ stok, const float* __restrict__ sw,
    const u16* __restrict__ heb, const u16* __restrict__ w2b,
    const float* __restrict__ b2all, float* __restrict__ out)
{
    __shared__ u16 As[ATILE];
    __shared__ u16 Bs[ATILE];
    int x = blockIdx.x, yb = blockIdx.y;
    if (yb < 128) {
        if (x == 7) return;
        int e = x, mt = yb >> 3, nt = yb & 7;
        int count = ci[CI_COUNT+e];
        int m0 = mt*BM;
        if (m0 >= count) return;
        gemm2_body(As, Bs, heb, w2b + (size_t)e*D_*HP, b2all + e*D_,
                   sw, ci[CI_OFF+e], m0, min(BM, count-m0), nt, out, stok);
    } else {
        int idx = (yb - 128)*8 + x;       // 0..127 (16*8)
        int mt = idx >> 3, nt = idx & 7;
        gemm2_body(As, Bs, heb, w2b + (size_t)7*D_*HP, b2all + 7*D_,
                   sw, SHARED_BASE, mt*BM, BM, nt, out, stok);
    }
}

extern "C" void kernel_launch(void* const* d_in, const int* in_sizes, int n_in,
                              void* d_out, int out_size, void* d_ws, size_t ws_size,
                              hipStream_t stream)
{
    const float* x   = (const float*)d_in[0];
    const float* Wg  = (const float*)d_in[1];
    const float* W1  = (const float*)d_in[2];
    const float* b1  = (const float*)d_in[3];
    const float* W2  = (const float*)d_in[4];
    const float* b2  = (const float*)d_in[5];
    const float* Ws1 = (const float*)d_in[6];
    const float* bs1 = (const float*)d_in[7];
    const float* Ws2 = (const float*)d_in[8];
    const float* bs2 = (const float*)d_in[9];
    float* out = (float*)d_out;
    char* ws = (char*)d_ws;

    int*   ci    = (int*)(ws + WS_CTRL);
    int*   tidx  = (int*)(ws + WS_TIDX);
    float* tw    = (float*)(ws + WS_TW);
    float* probs = (float*)(ws + WS_PROB);
    float* lse2  = (float*)(ws + WS_LSE2);
    int*   stok  = (int*)(ws + WS_STOK);
    float* sw    = (float*)(ws + WS_SW);
    float* b1all = (float*)(ws + WS_B1);
    float* b2all = (float*)(ws + WS_B2);
    u16*   xb    = (u16*)(ws + WS_XB);
    u16*   w1b   = (u16*)(ws + WS_W1B);
    u16*   w2b   = (u16*)(ws + WS_W2B);
    u16*   heb   = (u16*)(ws + WS_HEB);

    // out = 0 (all GEMM2 contributions are atomicAdd; finalize writes loss scalars after)
    hipMemsetAsync(d_out, 0, (size_t)out_size*sizeof(float), stream);

    // k1: router (512) || W1 + b1 convert, 4-deep ILP (1536) — zero LDS
    prep_kernel<<<2048, 256, 0, stream>>>(x, Wg, W1, Ws1, b1, bs1,
                                          tidx, tw, probs, lse2, xb, w1b, b1all);
    // k2: finalize || W2 + b2 convert (pure streaming, no GEMM stragglers)
    k2_kernel<<<513, 512, 0, stream>>>(W2, Ws2, b2, bs2, w2b, b2all,
                                       tidx, tw, probs, lse2, ci, stok, sw, out);
    // k3: ALL GEMM1: routed (expert->XCD pinned) || shared (spread over XCDs)
    k3_kernel<<<dim3(8, 176 + 22), 512, 0, stream>>>(ci, stok, xb, w1b, b1all, heb);
    // k4: ALL GEMM2: routed (XCD pinned) || shared, weighted atomic accumulate
    k4_kernel<<<dim3(8, 128 + 16), 512, 0, stream>>>(ci, stok, sw, heb, w2b, b2all, out);
}

// Round 13
// 137.049 us; speedup vs baseline: 1.1978x; 1.1978x over previous
//
#include <hip/hip_runtime.h>
#include <hip/hip_bf16.h>
#include <math.h>

typedef unsigned short u16;
typedef __attribute__((ext_vector_type(8))) short bf16x8;
typedef __attribute__((ext_vector_type(4))) float f32x4;

constexpr int D_ = 1024;
constexpr int H_ = 1365;
constexpr int E_ = 7;
constexpr int NTOK = 2048;
constexpr int HP = 1408;          // H padded to multiple of 64
constexpr int NE = 8;             // 7 routed + 1 shared
constexpr int SHARED_BASE = 4096;
constexpr int SLOTS = 6144;

#define CI_COUNT 0
#define CI_OFF   8

constexpr size_t WS_CTRL = 0;
constexpr size_t WS_TIDX = 256;
constexpr size_t WS_TW   = WS_TIDX + (size_t)NTOK*2*4;
constexpr size_t WS_PROB = WS_TW   + (size_t)NTOK*2*4;
constexpr size_t WS_LSE2 = WS_PROB + (size_t)NTOK*8*4;
constexpr size_t WS_STOK = WS_LSE2 + (size_t)NTOK*4;
constexpr size_t WS_SW   = WS_STOK + (size_t)SLOTS*4;
constexpr size_t WS_B1   = WS_SW   + (size_t)SLOTS*4;
constexpr size_t WS_B2   = WS_B1   + (size_t)NE*H_*4;
constexpr size_t WS_XB   = ((WS_B2 + (size_t)NE*D_*4) + 255) & ~(size_t)255;
constexpr size_t WS_W1B  = WS_XB  + (size_t)NTOK*D_*2;
constexpr size_t WS_W2B  = WS_W1B + (size_t)NE*H_*D_*2;
constexpr size_t WS_HEB  = WS_W2B + (size_t)NE*D_*HP*2;

__device__ __forceinline__ u16 f2bf(float f) {
    __hip_bfloat16 h = __float2bfloat16(f);
    return __builtin_bit_cast(u16, h);
}

__device__ __forceinline__ void gload_lds16(const u16* g, u16* l) {
    __builtin_amdgcn_global_load_lds(
        (const __attribute__((address_space(1))) void*)g,
        (__attribute__((address_space(3))) void*)l, 16, 0, 0);
}

__device__ __forceinline__ uint4 pack8(float4 a, float4 b) {
    union { u16 h[8]; uint4 v; } u;
    u.h[0]=f2bf(a.x); u.h[1]=f2bf(a.y); u.h[2]=f2bf(a.z); u.h[3]=f2bf(a.w);
    u.h[4]=f2bf(b.x); u.h[5]=f2bf(b.y); u.h[6]=f2bf(b.z); u.h[7]=f2bf(b.w);
    return u.v;
}

// tanh-form GELU (|err| ~3e-3, below bf16 quantization of He)
__device__ __forceinline__ float fast_gelu(float v) {
    float u = 0.7978845608f * v * (1.f + 0.044715f * v * v);
    float e = __expf(2.f * u);
    float t = 1.f - 2.f / (e + 1.f);
    return 0.5f * v * (1.f + t);
}

// ===== GEMM core: 128x128 block, BK=64, SINGLE-buffer 32KB LDS, 512 thr / 8 waves =====
#define BM 128
#define BN 128
#define KSTEP 64
#define ATILE (BM*KSTEP)    // 8192 elems = 16 KiB

#define MFMA16(a,b,c) __builtin_amdgcn_mfma_f32_16x16x32_bf16(a, b, c, 0, 0, 0)

template<bool USE_STOK>
__device__ __forceinline__ void gemm1_body(u16* As, u16* Bs,
    const u16* xb, const u16* w1e, const float* b1e,
    const int* stok, int offset, int m0, int valid, int nt,
    u16* heb)
{
    int t = threadIdx.x, wid = t >> 6, lane = t & 63;
    int rl = lane >> 3, cl = lane & 7;
    int sg = cl ^ rl;                    // pre-swizzled 16B-chunk (involution on row&7)

    const u16* aP[2]; const u16* bP[2]; int dOff[2];
    #pragma unroll
    for (int c = 0; c < 2; c++) {
        int row = wid*16 + c*8 + rl;
        int ar = min(row, valid-1);
        int tok = USE_STOK ? stok[offset + m0 + ar] : (m0 + ar);
        aP[c] = xb + (size_t)tok*D_ + sg*8;
        int jg = min(nt*BN + row, H_-1);
        bP[c] = w1e + (size_t)jg*D_ + sg*8;
        dOff[c] = (wid*16 + c*8)*KSTEP;
    }

    int wm = (wid >> 2)*64, wn = (wid & 3)*32;
    int frow = lane & 15, kgrp = lane >> 4, swz = frow & 7;
    f32x4 acc[4][2] = {};

    constexpr int nIter = D_/KSTEP;      // 16
    for (int tt = 0; tt < nIter; ++tt) {
        __syncthreads();
        int ko = tt*KSTEP;
        #pragma unroll
        for (int c = 0; c < 2; c++) {
            gload_lds16(aP[c]+ko, As + dOff[c]);
            gload_lds16(bP[c]+ko, Bs + dOff[c]);
        }
        __syncthreads();
        __builtin_amdgcn_s_setprio(1);
        #pragma unroll
        for (int s = 0; s < 2; s++) {
            int cc = ((s*4 + kgrp) ^ swz) * 8;
            bf16x8 af[4], bf[2];
            #pragma unroll
            for (int mf = 0; mf < 4; mf++)
                af[mf] = *(const bf16x8*)&As[(wm + mf*16 + frow)*KSTEP + cc];
            #pragma unroll
            for (int nf = 0; nf < 2; nf++)
                bf[nf] = *(const bf16x8*)&Bs[(wn + nf*16 + frow)*KSTEP + cc];
            #pragma unroll
            for (int mf = 0; mf < 4; mf++)
                #pragma unroll
                for (int nf = 0; nf < 2; nf++)
                    acc[mf][nf] = MFMA16(af[mf], bf[nf], acc[mf][nf]);
        }
        __builtin_amdgcn_s_setprio(0);
    }

    int r4 = (lane >> 4)*4, cEl = lane & 15;
    #pragma unroll
    for (int nf = 0; nf < 2; nf++) {
        int gcol = nt*BN + wn + nf*16 + cEl;
        bool cok = gcol < H_;
        float bias = cok ? b1e[gcol] : 0.f;
        #pragma unroll
        for (int mf = 0; mf < 4; mf++) {
            #pragma unroll
            for (int r = 0; r < 4; r++) {
                int row = wm + mf*16 + r4 + r;
                if (row < valid) {
                    float v = 0.f;
                    if (cok) v = fast_gelu(acc[mf][nf][r] + bias);
                    heb[(size_t)(offset + m0 + row)*HP + gcol] = f2bf(v);
                }
            }
        }
    }
}

// out contribution from He @ W2e^T + b2e.  MODE 0: plain store (shared, w=1);
// MODE 1: atomicAdd(out, w*v) (routed experts)
template<int MODE>
__device__ __forceinline__ void gemm2_body(u16* As, u16* Bs,
    const u16* heb, const u16* w2e, const float* b2e, const float* sw,
    int offset, int m0, int valid, int nt, float* out, const int* stok)
{
    int t = threadIdx.x, wid = t >> 6, lane = t & 63;
    int rl = lane >> 3, cl = lane & 7;
    int sg = cl ^ rl;

    const u16* aP[2]; const u16* bP[2]; int dOff[2];
    #pragma unroll
    for (int c = 0; c < 2; c++) {
        int row = wid*16 + c*8 + rl;
        int ar = min(row, valid-1);
        aP[c] = heb + (size_t)(offset + m0 + ar)*HP + sg*8;
        int jg = nt*BN + row;             // < 1024 always
        bP[c] = w2e + (size_t)jg*HP + sg*8;
        dOff[c] = (wid*16 + c*8)*KSTEP;
    }

    int wm = (wid >> 2)*64, wn = (wid & 3)*32;
    int frow = lane & 15, kgrp = lane >> 4, swz = frow & 7;
    f32x4 acc[4][2] = {};

    constexpr int nIter = HP/KSTEP;      // 22
    for (int tt = 0; tt < nIter; ++tt) {
        __syncthreads();
        int ko = tt*KSTEP;
        #pragma unroll
        for (int c = 0; c < 2; c++) {
            gload_lds16(aP[c]+ko, As + dOff[c]);
            gload_lds16(bP[c]+ko, Bs + dOff[c]);
        }
        __syncthreads();
        __builtin_amdgcn_s_setprio(1);
        #pragma unroll
        for (int s = 0; s < 2; s++) {
            int cc = ((s*4 + kgrp) ^ swz) * 8;
            bf16x8 af[4], bf[2];
            #pragma unroll
            for (int mf = 0; mf < 4; mf++)
                af[mf] = *(const bf16x8*)&As[(wm + mf*16 + frow)*KSTEP + cc];
            #pragma unroll
            for (int nf = 0; nf < 2; nf++)
                bf[nf] = *(const bf16x8*)&Bs[(wn + nf*16 + frow)*KSTEP + cc];
            #pragma unroll
            for (int mf = 0; mf < 4; mf++)
                #pragma unroll
                for (int nf = 0; nf < 2; nf++)
                    acc[mf][nf] = MFMA16(af[mf], bf[nf], acc[mf][nf]);
        }
        __builtin_amdgcn_s_setprio(0);
    }

    int r4 = (lane >> 4)*4, cEl = lane & 15;
    #pragma unroll
    for (int nf = 0; nf < 2; nf++) {
        int gcol = nt*BN + wn + nf*16 + cEl;
        float bias = b2e[gcol];
        #pragma unroll
        for (int mf = 0; mf < 4; mf++) {
            #pragma unroll
            for (int r = 0; r < 4; r++) {
                int row = wm + mf*16 + r4 + r;
                if (row < valid) {
                    if (MODE == 0) {
                        out[(size_t)(m0 + row)*D_ + gcol] = acc[mf][nf][r] + bias;
                    } else {
                        int slot = offset + m0 + row;
                        atomicAdd(out + (size_t)stok[slot]*D_ + gcol,
                                  sw[slot]*(acc[mf][nf][r] + bias));
                    }
                }
            }
        }
    }
}

// ================= finalize (512 threads): counts, offsets, losses, scatter =================
__device__ void finalize_body(char* big, char* small,
    const int* tidx, const float* tw, const float* probs, const float* lse2,
    int* ci, int* stok, float* sw, float* out)
{
    int*   lt   = (int*)big;                // 4096 ints (16 KiB)
    float* psum = (float*)small;
    float* lsum = (float*)(small + 32);
    int*   cntS = (int*)(small + 64);
    int*   offS = (int*)(small + 96);
    int t = threadIdx.x;
    if (t < 8) { psum[t] = 0.f; cntS[t] = 0; }
    if (t == 0) *lsum = 0.f;
    for (int i = t; i < NTOK*2; i += 512) lt[i] = tidx[i];
    __syncthreads();
    float lp[E_] = {}; float ll = 0.f;
    for (int n = t; n < NTOK; n += 512) {
        #pragma unroll
        for (int e = 0; e < E_; e++) lp[e] += probs[n*8+e];
        ll += lse2[n];
    }
    #pragma unroll
    for (int e = 0; e < E_; e++) atomicAdd(&psum[e], lp[e]);
    atomicAdd(lsum, ll);
    int wid = t >> 6, lane = t & 63;
    if (wid < 7) {
        int c = 0;
        for (int i = lane; i < NTOK*2; i += 64) c += (lt[i] == wid) ? 1 : 0;
        #pragma unroll
        for (int m = 32; m >= 1; m >>= 1) c += __shfl_xor(c, m);
        if (lane == 0) cntS[wid] = c;
    } else {
        for (int n = lane; n < NTOK; n += 64) {
            stok[SHARED_BASE+n] = n; sw[SHARED_BASE+n] = 1.f;
        }
    }
    __syncthreads();
    if (t == 0) {
        int o = 0;
        for (int e = 0; e < E_; e++) { offS[e] = o; o += cntS[e]; }
        offS[7] = SHARED_BASE; cntS[7] = NTOK;
        float la = 0.f;
        for (int e = 0; e < E_; e++)
            la += ((float)cntS[e] / (float)(NTOK*2)) * (psum[e] / (float)NTOK);
        out[(size_t)NTOK*D_]     = 0.01f * 7.f * la;
        out[(size_t)NTOK*D_ + 1] = 0.001f * (*lsum) / (float)NTOK;
        #pragma unroll
        for (int e = 0; e < 8; e++) { ci[CI_COUNT+e] = cntS[e]; ci[CI_OFF+e] = offS[e]; }
    }
    __syncthreads();
    if (wid < 7) {
        int base = offS[wid], run = 0;
        for (int c0 = 0; c0 < NTOK*2; c0 += 64) {
            bool m = (lt[c0 + lane] == wid);
            unsigned long long bal = __ballot(m);
            int pre = __popcll(bal & ((1ull << lane) - 1ull));
            if (m) {
                int i = c0 + lane;
                int s = base + run + pre;
                stok[s] = i >> 1; sw[s] = tw[i];
            }
            run += __popcll(bal);
        }
    }
}

// ==== k1: router (0..511) || W1+b1 convert, 4-deep ILP (512..2047) — NO LDS ====
__global__ void prep_kernel(
    const float* __restrict__ x, const float* __restrict__ Wg,
    const float* __restrict__ W1, const float* __restrict__ Ws1,
    const float* __restrict__ b1, const float* __restrict__ bs1,
    int* __restrict__ tidx, float* __restrict__ tw,
    float* __restrict__ probs, float* __restrict__ lse2,
    u16* __restrict__ xb, u16* __restrict__ w1b, float* __restrict__ b1all)
{
    int b = blockIdx.x;
    if (b < 512) {
        int wid = threadIdx.x >> 6, lane = threadIdx.x & 63;
        int n = b*4 + wid;
        float p[E_] = {};
        const float* xr = x + (size_t)n*D_;
        u16* xbr = xb + (size_t)n*D_;
        #pragma unroll
        for (int j = 0; j < 4; j++) {
            int d0 = lane*4 + j*256;
            float4 xv = *(const float4*)(xr + d0);
            ushort4 h;
            h.x = f2bf(xv.x); h.y = f2bf(xv.y); h.z = f2bf(xv.z); h.w = f2bf(xv.w);
            *(ushort4*)(xbr + d0) = h;
            #pragma unroll
            for (int e = 0; e < E_; e++) {
                float4 wv = *(const float4*)(Wg + e*D_ + d0);
                p[e] += xv.x*wv.x + xv.y*wv.y + xv.z*wv.z + xv.w*wv.w;
            }
        }
        #pragma unroll
        for (int e = 0; e < E_; e++) {
            float v = p[e];
            #pragma unroll
            for (int m = 32; m >= 1; m >>= 1) v += __shfl_xor(v, m);
            p[e] = v;
        }
        if (lane == 0) {
            float mx = p[0];
            #pragma unroll
            for (int e = 1; e < E_; e++) mx = fmaxf(mx, p[e]);
            float pr[E_], sum = 0.f;
            #pragma unroll
            for (int e = 0; e < E_; e++) { pr[e] = __expf(p[e]-mx); sum += pr[e]; }
            float lse = mx + logf(sum);
            int i0 = 0;
            #pragma unroll
            for (int e = 1; e < E_; e++) if (p[e] > p[i0]) i0 = e;
            int i1 = -1;
            #pragma unroll
            for (int e = 0; e < E_; e++) if (e != i0 && (i1 < 0 || p[e] > p[i1])) i1 = e;
            float g = expf(p[i1] - p[i0]);
            tidx[n*2] = i0; tidx[n*2+1] = i1;
            tw[n*2] = 1.f/(1.f+g); tw[n*2+1] = g/(1.f+g);
            float inv = 1.f/sum;
            #pragma unroll
            for (int e = 0; e < E_; e++) probs[n*8+e] = pr[e]*inv;
            lse2[n] = lse*lse;
        }
        return;
    }
    // ---- W1 convert: 4 strided uint4 groups per thread, all loads issued first ----
    const unsigned G1 = (unsigned)(NE*H_*D_/8);
    const unsigned NT = 1536u*256u;
    const unsigned W1FLAT = 7u*(unsigned)(H_*D_);
    unsigned tid = (unsigned)(b-512)*256u + threadIdx.x;
    unsigned i0 = tid, i1 = tid + NT, i2 = tid + 2u*NT, i3 = tid + 3u*NT;
    bool p3 = i3 < G1;
    float4 va0, vb0, va1, vb1, va2, vb2, va3, vb3;
    {
        const float* s0 = (i0*8u < W1FLAT) ? W1 + (size_t)i0*8u : Ws1 + ((size_t)i0*8u - W1FLAT);
        va0 = *(const float4*)s0; vb0 = *(const float4*)(s0+4);
        const float* s1 = (i1*8u < W1FLAT) ? W1 + (size_t)i1*8u : Ws1 + ((size_t)i1*8u - W1FLAT);
        va1 = *(const float4*)s1; vb1 = *(const float4*)(s1+4);
        const float* s2 = (i2*8u < W1FLAT) ? W1 + (size_t)i2*8u : Ws1 + ((size_t)i2*8u - W1FLAT);
        va2 = *(const float4*)s2; vb2 = *(const float4*)(s2+4);
        if (p3) {
            const float* s3 = (i3*8u < W1FLAT) ? W1 + (size_t)i3*8u : Ws1 + ((size_t)i3*8u - W1FLAT);
            va3 = *(const float4*)s3; vb3 = *(const float4*)(s3+4);
        }
    }
    ((uint4*)w1b)[i0] = pack8(va0, vb0);
    ((uint4*)w1b)[i1] = pack8(va1, vb1);
    ((uint4*)w1b)[i2] = pack8(va2, vb2);
    if (p3) ((uint4*)w1b)[i3] = pack8(va3, vb3);
    if (tid < 10920u) b1all[tid] = (tid < 9555u) ? b1[tid] : bs1[tid - 9555u];
}

// ===== k2: finalize (blk 0) || shared GEMM1 (1..176) || SHARED W2 + b2 (177..240) =====
__global__ __launch_bounds__(512, 8) void k2_kernel(
    const float* __restrict__ Ws2, const float* __restrict__ b2,
    const float* __restrict__ bs2,
    u16* __restrict__ w2b, float* __restrict__ b2all,
    const int* __restrict__ tidx, const float* __restrict__ tw,
    const float* __restrict__ probs, const float* __restrict__ lse2,
    int* __restrict__ ci, int* __restrict__ stok, float* __restrict__ sw,
    float* __restrict__ out,
    const u16* __restrict__ xb, const u16* __restrict__ w1b,
    const float* __restrict__ b1all, u16* __restrict__ heb)
{
    __shared__ u16 As[ATILE];
    __shared__ u16 Bs[ATILE];
    int b = blockIdx.x;
    if (b == 0) {
        finalize_body((char*)As, (char*)Bs, tidx, tw, probs, lse2, ci, stok, sw, out);
        return;
    }
    if (b <= 176) {
        int tdx = b - 1;
        int mt = tdx/11, nt = tdx - mt*11;
        gemm1_body<false>(As, Bs, xb, w1b + (size_t)7*H_*D_, b1all + 7*H_,
                          nullptr, SHARED_BASE, mt*BM, BM, nt, heb);
        return;
    }
    // ---- shared-expert W2 slice (1024 rows) + b2all copy ----
    unsigned tid = (unsigned)(b-177)*512u + threadIdx.x;   // 64 blocks -> 32768 threads
    if (tid < 8192u) b2all[tid] = (tid < 7168u) ? b2[tid] : bs2[tid - 7168u];
    int lane = threadIdx.x & 63;
    int rs0 = (((b-177)*8) + (threadIdx.x >> 6)) * 2;      // 0..1022 (shared-local row)
    #pragma unroll
    for (int j = 0; j < 2; j++) {
        int rs = rs0 + j;
        const float* src = Ws2 + (size_t)rs*(size_t)H_;
        u16* dst = w2b + (size_t)(7*D_ + rs)*HP;
        #pragma unroll
        for (int h0 = 0; h0 < HP; h0 += 64) {
            int h = h0 + lane;
            float v = (h < H_) ? src[h] : 0.f;
            dst[h] = f2bf(v);
        }
    }
}

// == k3: routed GEMM1 (XCD-pinned, yb<176) || shared GEMM2 (176..191) || routed W2 (192..247) ==
__global__ __launch_bounds__(512, 8) void k3_kernel(
    const int* __restrict__ ci, const int* __restrict__ stok,
    const u16* __restrict__ xb, const u16* __restrict__ w1b,
    const float* __restrict__ b1all, u16* __restrict__ heb,
    const float* __restrict__ W2, u16* __restrict__ w2b,
    const u16* __restrict__ w2b_c, const float* __restrict__ b2all,
    float* __restrict__ out)
{
    __shared__ u16 As[ATILE];
    __shared__ u16 Bs[ATILE];
    int x = blockIdx.x, yb = blockIdx.y;
    if (yb < 176) {
        if (x == 7) return;
        int e = x, mt = yb/11, nt = yb - mt*11;
        int count = ci[CI_COUNT+e];
        int m0 = mt*BM;
        if (m0 >= count) return;
        gemm1_body<true>(As, Bs, xb, w1b + (size_t)e*H_*D_, b1all + e*H_,
                         stok, ci[CI_OFF+e], m0, min(BM, count-m0), nt, heb);
    } else if (yb < 192) {
        int idx = (yb - 176)*8 + x;       // 0..127
        int mt = idx >> 3, nt = idx & 7;
        gemm2_body<0>(As, Bs, heb, w2b_c + (size_t)7*D_*HP, b2all + 7*D_,
                      nullptr, SHARED_BASE, mt*BM, BM, nt, out, nullptr);
    } else {
        // ---- routed W2 convert: wave per 2 rows, 448 blocks x 16 rows = 7168 rows ----
        int idx = (yb - 192)*8 + x;       // 0..447
        int lane = threadIdx.x & 63;
        int rw0 = idx*16 + (threadIdx.x >> 6)*2;
        #pragma unroll
        for (int j = 0; j < 2; j++) {
            int rw = rw0 + j;              // 0..7167
            int ec = rw >> 10, drow = rw & 1023;
            const float* src = W2 + ((size_t)ec*D_ + drow)*(size_t)H_;
            u16* dst = w2b + (size_t)rw*HP;
            #pragma unroll
            for (int h0 = 0; h0 < HP; h0 += 64) {
                int h = h0 + lane;
                float v = (h < H_) ? src[h] : 0.f;
                dst[h] = f2bf(v);
            }
        }
    }
}

// ===== k4: routed GEMM2 (XCD-pinned), atomicAdd into out =====
__global__ __launch_bounds__(512, 8) void k4_kernel(
    const int* __restrict__ ci, const int* __restrict__ stok, const float* __restrict__ sw,
    const u16* __restrict__ heb, const u16* __restrict__ w2b,
    const float* __restrict__ b2all, float* __restrict__ out)
{
    __shared__ u16 As[ATILE];
    __shared__ u16 Bs[ATILE];
    int x = blockIdx.x;
    if (x == 7) return;
    int yb = blockIdx.y;
    int e = x, mt = yb >> 3, nt = yb & 7;
    int count = ci[CI_COUNT+e];
    int m0 = mt*BM;
    if (m0 >= count) return;
    gemm2_body<1>(As, Bs, heb, w2b + (size_t)e*D_*HP, b2all + e*D_,
                  sw, ci[CI_OFF+e], m0, min(BM, count-m0), nt, out, stok);
}

extern "C" void kernel_launch(void* const* d_in, const int* in_sizes, int n_in,
                              void* d_out, int out_size, void* d_ws, size_t ws_size,
                              hipStream_t stream)
{
    const float* x   = (const float*)d_in[0];
    const float* Wg  = (const float*)d_in[1];
    const float* W1  = (const float*)d_in[2];
    const float* b1  = (const float*)d_in[3];
    const float* W2  = (const float*)d_in[4];
    const float* b2  = (const float*)d_in[5];
    const float* Ws1 = (const float*)d_in[6];
    const float* bs1 = (const float*)d_in[7];
    const float* Ws2 = (const float*)d_in[8];
    const float* bs2 = (const float*)d_in[9];
    float* out = (float*)d_out;
    char* ws = (char*)d_ws;

    int*   ci    = (int*)(ws + WS_CTRL);
    int*   tidx  = (int*)(ws + WS_TIDX);
    float* tw    = (float*)(ws + WS_TW);
    float* probs = (float*)(ws + WS_PROB);
    float* lse2  = (float*)(ws + WS_LSE2);
    int*   stok  = (int*)(ws + WS_STOK);
    float* sw    = (float*)(ws + WS_SW);
    float* b1all = (float*)(ws + WS_B1);
    float* b2all = (float*)(ws + WS_B2);
    u16*   xb    = (u16*)(ws + WS_XB);
    u16*   w1b   = (u16*)(ws + WS_W1B);
    u16*   w2b   = (u16*)(ws + WS_W2B);
    u16*   heb   = (u16*)(ws + WS_HEB);

    // k1: router (512) || W1 + b1 convert, 4-deep ILP (1536) — zero LDS
    prep_kernel<<<2048, 256, 0, stream>>>(x, Wg, W1, Ws1, b1, bs1,
                                          tidx, tw, probs, lse2, xb, w1b, b1all);
    // k2: finalize || shared GEMM1 (176) || SHARED-expert W2 + b2 convert (64)
    k2_kernel<<<241, 512, 0, stream>>>(Ws2, b2, bs2, w2b, b2all,
                                       tidx, tw, probs, lse2, ci, stok, sw, out,
                                       xb, w1b, b1all, heb);
    // k3: routed GEMM1 (XCD pinned) || shared GEMM2 (plain store) || ROUTED W2 convert
    k3_kernel<<<dim3(8, 176 + 16 + 56), 512, 0, stream>>>(ci, stok, xb, w1b, b1all, heb,
                                                          W2, w2b, w2b, b2all, out);
    // k4: routed GEMM2, weighted atomic accumulate
    k4_kernel<<<dim3(8, 128), 512, 0, stream>>>(ci, stok, sw, heb, w2b, b2all, out);
}

// Round 15
// 127.132 us; speedup vs baseline: 1.2913x; 1.0780x over previous
//
#include <hip/hip_runtime.h>
#include <hip/hip_bf16.h>
#include <math.h>

typedef unsigned short u16;
typedef __attribute__((ext_vector_type(8))) short bf16x8;
typedef __attribute__((ext_vector_type(4))) float f32x4;

constexpr int D_ = 1024;
constexpr int H_ = 1365;
constexpr int E_ = 7;
constexpr int NTOK = 2048;
constexpr int HP = 1408;          // H padded to multiple of 64
constexpr int NE = 8;             // 7 routed + 1 shared
constexpr int SHARED_BASE = 4096;
constexpr int SLOTS = 6144;

#define CI_COUNT 0
#define CI_OFF   8

constexpr size_t WS_CTRL = 0;
constexpr size_t WS_TIDX = 256;
constexpr size_t WS_TW   = WS_TIDX + (size_t)NTOK*2*4;
constexpr size_t WS_PROB = WS_TW   + (size_t)NTOK*2*4;
constexpr size_t WS_LSE2 = WS_PROB + (size_t)NTOK*8*4;
constexpr size_t WS_STOK = WS_LSE2 + (size_t)NTOK*4;
constexpr size_t WS_SW   = WS_STOK + (size_t)SLOTS*4;
constexpr size_t WS_B1   = WS_SW   + (size_t)SLOTS*4;
constexpr size_t WS_B2   = WS_B1   + (size_t)NE*H_*4;
constexpr size_t WS_XB   = ((WS_B2 + (size_t)NE*D_*4) + 255) & ~(size_t)255;
constexpr size_t WS_W1B  = WS_XB  + (size_t)NTOK*D_*2;
constexpr size_t WS_W2B  = WS_W1B + (size_t)NE*H_*D_*2;
constexpr size_t WS_HEB  = WS_W2B + (size_t)NE*D_*HP*2;

__device__ __forceinline__ u16 f2bf(float f) {
    __hip_bfloat16 h = __float2bfloat16(f);
    return __builtin_bit_cast(u16, h);
}

__device__ __forceinline__ void gload_lds16(const u16* g, u16* l) {
    __builtin_amdgcn_global_load_lds(
        (const __attribute__((address_space(1))) void*)g,
        (__attribute__((address_space(3))) void*)l, 16, 0, 0);
}

__device__ __forceinline__ uint4 pack8(float4 a, float4 b) {
    union { u16 h[8]; uint4 v; } u;
    u.h[0]=f2bf(a.x); u.h[1]=f2bf(a.y); u.h[2]=f2bf(a.z); u.h[3]=f2bf(a.w);
    u.h[4]=f2bf(b.x); u.h[5]=f2bf(b.y); u.h[6]=f2bf(b.z); u.h[7]=f2bf(b.w);
    return u.v;
}

// tanh-form GELU (|err| ~3e-3, below bf16 quantization of He)
__device__ __forceinline__ float fast_gelu(float v) {
    float u = 0.7978845608f * v * (1.f + 0.044715f * v * v);
    float e = __expf(2.f * u);
    float t = 1.f - 2.f / (e + 1.f);
    return 0.5f * v * (1.f + t);
}

// ===== GEMM core: 64x128 block, BK=64, single-buffer 24KB LDS, 512 thr / 8 waves =====
// Wave tile 32x32 (2x2 16x16x32 frags, measured-0-conflict swizzle). 4 blocks/CU.
#define BN 128
#define KSTEP 64
#define ASZ (64*KSTEP)      // 4096 elems = 8 KiB
#define BSZ (128*KSTEP)     // 8192 elems = 16 KiB

#define MFMA16(a,b,c) __builtin_amdgcn_mfma_f32_16x16x32_bf16(a, b, c, 0, 0, 0)

template<bool USE_STOK>
__device__ __forceinline__ void gemm1_body(u16* As, u16* Bs,
    const u16* xb, const u16* w1e, const float* b1e,
    const int* stok, int offset, int m0, int valid, int nt,
    u16* heb)
{
    int t = threadIdx.x, wid = t >> 6, lane = t & 63;
    int rl = lane >> 3, cl = lane & 7;
    int sg = cl ^ rl;                    // pre-swizzled 16B-chunk (involution on row&7)

    int arow = wid*8 + rl;
    int ar = min(arow, valid-1);
    int tok = USE_STOK ? stok[offset + m0 + ar] : (m0 + ar);
    const u16* aP = xb + (size_t)tok*D_ + sg*8;
    int dOffA = wid*8*KSTEP;
    const u16* bP[2]; int dOffB[2];
    #pragma unroll
    for (int c = 0; c < 2; c++) {
        int brow = wid*16 + c*8 + rl;
        int jg = min(nt*BN + brow, H_-1);
        bP[c] = w1e + (size_t)jg*D_ + sg*8;
        dOffB[c] = (wid*16 + c*8)*KSTEP;
    }

    int wm = (wid >> 2)*32, wn = (wid & 3)*32;
    int frow = lane & 15, kgrp = lane >> 4, swz = frow & 7;
    f32x4 acc[2][2] = {};

    constexpr int nIter = D_/KSTEP;      // 16
    for (int tt = 0; tt < nIter; ++tt) {
        __syncthreads();
        int ko = tt*KSTEP;
        gload_lds16(aP+ko, As + dOffA);
        #pragma unroll
        for (int c = 0; c < 2; c++) gload_lds16(bP[c]+ko, Bs + dOffB[c]);
        __syncthreads();
        __builtin_amdgcn_s_setprio(1);
        #pragma unroll
        for (int s = 0; s < 2; s++) {
            int cc = ((s*4 + kgrp) ^ swz) * 8;
            bf16x8 af[2], bf[2];
            #pragma unroll
            for (int mf = 0; mf < 2; mf++)
                af[mf] = *(const bf16x8*)&As[(wm + mf*16 + frow)*KSTEP + cc];
            #pragma unroll
            for (int nf = 0; nf < 2; nf++)
                bf[nf] = *(const bf16x8*)&Bs[(wn + nf*16 + frow)*KSTEP + cc];
            #pragma unroll
            for (int mf = 0; mf < 2; mf++)
                #pragma unroll
                for (int nf = 0; nf < 2; nf++)
                    acc[mf][nf] = MFMA16(af[mf], bf[nf], acc[mf][nf]);
        }
        __builtin_amdgcn_s_setprio(0);
    }

    int r4 = (lane >> 4)*4, cEl = lane & 15;
    #pragma unroll
    for (int nf = 0; nf < 2; nf++) {
        int gcol = nt*BN + wn + nf*16 + cEl;
        bool cok = gcol < H_;
        float bias = cok ? b1e[gcol] : 0.f;
        #pragma unroll
        for (int mf = 0; mf < 2; mf++) {
            #pragma unroll
            for (int r = 0; r < 4; r++) {
                int row = wm + mf*16 + r4 + r;
                if (row < valid) {
                    float v = 0.f;
                    if (cok) v = fast_gelu(acc[mf][nf][r] + bias);
                    heb[(size_t)(offset + m0 + row)*HP + gcol] = f2bf(v);
                }
            }
        }
    }
}

// out contribution from He @ W2e^T + b2e.  MODE 0: plain store (shared, w=1);
// MODE 1: atomicAdd(out, w*v) (routed experts)  — MODE 0 and MODE 1 must run in
// SEPARATE kernel launches (store would race with atomics otherwise).
template<int MODE>
__device__ __forceinline__ void gemm2_body(u16* As, u16* Bs,
    const u16* heb, const u16* w2e, const float* b2e, const float* sw,
    int offset, int m0, int valid, int nt, float* out, const int* stok)
{
    int t = threadIdx.x, wid = t >> 6, lane = t & 63;
    int rl = lane >> 3, cl = lane & 7;
    int sg = cl ^ rl;

    int arow = wid*8 + rl;
    int ar = min(arow, valid-1);
    const u16* aP = heb + (size_t)(offset + m0 + ar)*HP + sg*8;
    int dOffA = wid*8*KSTEP;
    const u16* bP[2]; int dOffB[2];
    #pragma unroll
    for (int c = 0; c < 2; c++) {
        int brow = wid*16 + c*8 + rl;
        int jg = nt*BN + brow;            // < 1024 always
        bP[c] = w2e + (size_t)jg*HP + sg*8;
        dOffB[c] = (wid*16 + c*8)*KSTEP;
    }

    int wm = (wid >> 2)*32, wn = (wid & 3)*32;
    int frow = lane & 15, kgrp = lane >> 4, swz = frow & 7;
    f32x4 acc[2][2] = {};

    constexpr int nIter = HP/KSTEP;      // 22
    for (int tt = 0; tt < nIter; ++tt) {
        __syncthreads();
        int ko = tt*KSTEP;
        gload_lds16(aP+ko, As + dOffA);
        #pragma unroll
        for (int c = 0; c < 2; c++) gload_lds16(bP[c]+ko, Bs + dOffB[c]);
        __syncthreads();
        __builtin_amdgcn_s_setprio(1);
        #pragma unroll
        for (int s = 0; s < 2; s++) {
            int cc = ((s*4 + kgrp) ^ swz) * 8;
            bf16x8 af[2], bf[2];
            #pragma unroll
            for (int mf = 0; mf < 2; mf++)
                af[mf] = *(const bf16x8*)&As[(wm + mf*16 + frow)*KSTEP + cc];
            #pragma unroll
            for (int nf = 0; nf < 2; nf++)
                bf[nf] = *(const bf16x8*)&Bs[(wn + nf*16 + frow)*KSTEP + cc];
            #pragma unroll
            for (int mf = 0; mf < 2; mf++)
                #pragma unroll
                for (int nf = 0; nf < 2; nf++)
                    acc[mf][nf] = MFMA16(af[mf], bf[nf], acc[mf][nf]);
        }
        __builtin_amdgcn_s_setprio(0);
    }

    int r4 = (lane >> 4)*4, cEl = lane & 15;
    #pragma unroll
    for (int nf = 0; nf < 2; nf++) {
        int gcol = nt*BN + wn + nf*16 + cEl;
        float bias = b2e[gcol];
        #pragma unroll
        for (int mf = 0; mf < 2; mf++) {
            #pragma unroll
            for (int r = 0; r < 4; r++) {
                int row = wm + mf*16 + r4 + r;
                if (row < valid) {
                    if (MODE == 0) {
                        out[(size_t)(m0 + row)*D_ + gcol] = acc[mf][nf][r] + bias;
                    } else {
                        int slot = offset + m0 + row;
                        atomicAdd(out + (size_t)stok[slot]*D_ + gcol,
                                  sw[slot]*(acc[mf][nf][r] + bias));
                    }
                }
            }
        }
    }
}

// ================= finalize (512 threads): counts, offsets, losses, scatter =================
__device__ void finalize_body(char* big, char* small,
    const int* tidx, const float* tw, const float* probs, const float* lse2,
    int* ci, int* stok, float* sw, float* out)
{
    int*   lt   = (int*)big;                // 4096 ints (16 KiB)
    float* psum = (float*)small;
    float* lsum = (float*)(small + 32);
    int*   cntS = (int*)(small + 64);
    int*   offS = (int*)(small + 96);
    int t = threadIdx.x;
    if (t < 8) { psum[t] = 0.f; cntS[t] = 0; }
    if (t == 0) *lsum = 0.f;
    for (int i = t; i < NTOK*2; i += 512) lt[i] = tidx[i];
    __syncthreads();
    float lp[E_] = {}; float ll = 0.f;
    for (int n = t; n < NTOK; n += 512) {
        #pragma unroll
        for (int e = 0; e < E_; e++) lp[e] += probs[n*8+e];
        ll += lse2[n];
    }
    #pragma unroll
    for (int e = 0; e < E_; e++) atomicAdd(&psum[e], lp[e]);
    atomicAdd(lsum, ll);
    int wid = t >> 6, lane = t & 63;
    if (wid < 7) {
        int c = 0;
        for (int i = lane; i < NTOK*2; i += 64) c += (lt[i] == wid) ? 1 : 0;
        #pragma unroll
        for (int m = 32; m >= 1; m >>= 1) c += __shfl_xor(c, m);
        if (lane == 0) cntS[wid] = c;
    } else {
        for (int n = lane; n < NTOK; n += 64) {
            stok[SHARED_BASE+n] = n; sw[SHARED_BASE+n] = 1.f;
        }
    }
    __syncthreads();
    if (t == 0) {
        int o = 0;
        for (int e = 0; e < E_; e++) { offS[e] = o; o += cntS[e]; }
        offS[7] = SHARED_BASE; cntS[7] = NTOK;
        float la = 0.f;
        for (int e = 0; e < E_; e++)
            la += ((float)cntS[e] / (float)(NTOK*2)) * (psum[e] / (float)NTOK);
        out[(size_t)NTOK*D_]     = 0.01f * 7.f * la;
        out[(size_t)NTOK*D_ + 1] = 0.001f * (*lsum) / (float)NTOK;
        #pragma unroll
        for (int e = 0; e < 8; e++) { ci[CI_COUNT+e] = cntS[e]; ci[CI_OFF+e] = offS[e]; }
    }
    __syncthreads();
    if (wid < 7) {
        int base = offS[wid], run = 0;
        for (int c0 = 0; c0 < NTOK*2; c0 += 64) {
            bool m = (lt[c0 + lane] == wid);
            unsigned long long bal = __ballot(m);
            int pre = __popcll(bal & ((1ull << lane) - 1ull));
            if (m) {
                int i = c0 + lane;
                int s = base + run + pre;
                stok[s] = i >> 1; sw[s] = tw[i];
            }
            run += __popcll(bal);
        }
    }
}

// ==== k1: router (0..511) || W1+b1 convert, 4-deep ILP (512..2047) — NO LDS ====
__global__ void prep_kernel(
    const float* __restrict__ x, const float* __restrict__ Wg,
    const float* __restrict__ W1, const float* __restrict__ Ws1,
    const float* __restrict__ b1, const float* __restrict__ bs1,
    int* __restrict__ tidx, float* __restrict__ tw,
    float* __restrict__ probs, float* __restrict__ lse2,
    u16* __restrict__ xb, u16* __restrict__ w1b, float* __restrict__ b1all)
{
    int b = blockIdx.x;
    if (b < 512) {
        int wid = threadIdx.x >> 6, lane = threadIdx.x & 63;
        int n = b*4 + wid;
        float p[E_] = {};
        const float* xr = x + (size_t)n*D_;
        u16* xbr = xb + (size_t)n*D_;
        #pragma unroll
        for (int j = 0; j < 4; j++) {
            int d0 = lane*4 + j*256;
            float4 xv = *(const float4*)(xr + d0);
            ushort4 h;
            h.x = f2bf(xv.x); h.y = f2bf(xv.y); h.z = f2bf(xv.z); h.w = f2bf(xv.w);
            *(ushort4*)(xbr + d0) = h;
            #pragma unroll
            for (int e = 0; e < E_; e++) {
                float4 wv = *(const float4*)(Wg + e*D_ + d0);
                p[e] += xv.x*wv.x + xv.y*wv.y + xv.z*wv.z + xv.w*wv.w;
            }
        }
        #pragma unroll
        for (int e = 0; e < E_; e++) {
            float v = p[e];
            #pragma unroll
            for (int m = 32; m >= 1; m >>= 1) v += __shfl_xor(v, m);
            p[e] = v;
        }
        if (lane == 0) {
            float mx = p[0];
            #pragma unroll
            for (int e = 1; e < E_; e++) mx = fmaxf(mx, p[e]);
            float pr[E_], sum = 0.f;
            #pragma unroll
            for (int e = 0; e < E_; e++) { pr[e] = __expf(p[e]-mx); sum += pr[e]; }
            float lse = mx + logf(sum);
            int i0 = 0;
            #pragma unroll
            for (int e = 1; e < E_; e++) if (p[e] > p[i0]) i0 = e;
            int i1 = -1;
            #pragma unroll
            for (int e = 0; e < E_; e++) if (e != i0 && (i1 < 0 || p[e] > p[i1])) i1 = e;
            float g = expf(p[i1] - p[i0]);
            tidx[n*2] = i0; tidx[n*2+1] = i1;
            tw[n*2] = 1.f/(1.f+g); tw[n*2+1] = g/(1.f+g);
            float inv = 1.f/sum;
            #pragma unroll
            for (int e = 0; e < E_; e++) probs[n*8+e] = pr[e]*inv;
            lse2[n] = lse*lse;
        }
        return;
    }
    // ---- W1 convert: 4 strided uint4 groups per thread, all loads issued first ----
    const unsigned G1 = (unsigned)(NE*H_*D_/8);
    const unsigned NT = 1536u*256u;
    const unsigned W1FLAT = 7u*(unsigned)(H_*D_);
    unsigned tid = (unsigned)(b-512)*256u + threadIdx.x;
    unsigned i0 = tid, i1 = tid + NT, i2 = tid + 2u*NT, i3 = tid + 3u*NT;
    bool p3 = i3 < G1;
    float4 va0, vb0, va1, vb1, va2, vb2, va3, vb3;
    {
        const float* s0 = (i0*8u < W1FLAT) ? W1 + (size_t)i0*8u : Ws1 + ((size_t)i0*8u - W1FLAT);
        va0 = *(const float4*)s0; vb0 = *(const float4*)(s0+4);
        const float* s1 = (i1*8u < W1FLAT) ? W1 + (size_t)i1*8u : Ws1 + ((size_t)i1*8u - W1FLAT);
        va1 = *(const float4*)s1; vb1 = *(const float4*)(s1+4);
        const float* s2 = (i2*8u < W1FLAT) ? W1 + (size_t)i2*8u : Ws1 + ((size_t)i2*8u - W1FLAT);
        va2 = *(const float4*)s2; vb2 = *(const float4*)(s2+4);
        if (p3) {
            const float* s3 = (i3*8u < W1FLAT) ? W1 + (size_t)i3*8u : Ws1 + ((size_t)i3*8u - W1FLAT);
            va3 = *(const float4*)s3; vb3 = *(const float4*)(s3+4);
        }
    }
    ((uint4*)w1b)[i0] = pack8(va0, vb0);
    ((uint4*)w1b)[i1] = pack8(va1, vb1);
    ((uint4*)w1b)[i2] = pack8(va2, vb2);
    if (p3) ((uint4*)w1b)[i3] = pack8(va3, vb3);
    if (tid < 10920u) b1all[tid] = (tid < 9555u) ? b1[tid] : bs1[tid - 9555u];
}

// ===== k2: finalize (blk 0) || shared GEMM1 (1..352) || SHARED W2 + b2 (353..416) =====
__global__ __launch_bounds__(512, 8) void k2_kernel(
    const float* __restrict__ Ws2, const float* __restrict__ b2,
    const float* __restrict__ bs2,
    u16* __restrict__ w2b, float* __restrict__ b2all,
    const int* __restrict__ tidx, const float* __restrict__ tw,
    const float* __restrict__ probs, const float* __restrict__ lse2,
    int* __restrict__ ci, int* __restrict__ stok, float* __restrict__ sw,
    float* __restrict__ out,
    const u16* __restrict__ xb, const u16* __restrict__ w1b,
    const float* __restrict__ b1all, u16* __restrict__ heb)
{
    __shared__ u16 As[ASZ];
    __shared__ u16 Bs[BSZ];
    int b = blockIdx.x;
    if (b == 0) {
        finalize_body((char*)Bs, (char*)As, tidx, tw, probs, lse2, ci, stok, sw, out);
        return;
    }
    if (b <= 352) {
        int tdx = b - 1;
        int mt = tdx/11, nt = tdx - mt*11;       // mt 0..31, nt 0..10
        gemm1_body<false>(As, Bs, xb, w1b + (size_t)7*H_*D_, b1all + 7*H_,
                          nullptr, SHARED_BASE, mt*64, 64, nt, heb);
        return;
    }
    // ---- shared-expert W2 slice (1024 rows) + b2all copy ----
    unsigned tid = (unsigned)(b-353)*512u + threadIdx.x;   // 64 blocks
    if (tid < 8192u) b2all[tid] = (tid < 7168u) ? b2[tid] : bs2[tid - 7168u];
    int lane = threadIdx.x & 63;
    int rs0 = (((b-353)*8) + (threadIdx.x >> 6)) * 2;      // 0..1022
    #pragma unroll
    for (int j = 0; j < 2; j++) {
        int rs = rs0 + j;
        const float* src = Ws2 + (size_t)rs*(size_t)H_;
        u16* dst = w2b + (size_t)(7*D_ + rs)*HP;
        #pragma unroll
        for (int h0 = 0; h0 < HP; h0 += 64) {
            int h = h0 + lane;
            float v = (h < H_) ? src[h] : 0.f;
            dst[h] = f2bf(v);
        }
    }
}

// == k3: routed GEMM1 (XCD-pinned, yb<352) || shared GEMM2 store (352..383) || routed W2 (384..439) ==
__global__ __launch_bounds__(512, 8) void k3_kernel(
    const int* __restrict__ ci, const int* __restrict__ stok,
    const u16* __restrict__ xb, const u16* __restrict__ w1b,
    const float* __restrict__ b1all, u16* __restrict__ heb,
    const float* __restrict__ W2, u16* __restrict__ w2b,
    const u16* __restrict__ w2b_c, const float* __restrict__ b2all,
    float* __restrict__ out)
{
    __shared__ u16 As[ASZ];
    __shared__ u16 Bs[BSZ];
    int x = blockIdx.x, yb = blockIdx.y;
    if (yb < 352) {
        if (x == 7) return;
        int e = x, mt = yb/11, nt = yb - mt*11;   // mt 0..31
        int count = ci[CI_COUNT+e];
        int m0 = mt*64;
        if (m0 >= count) return;
        gemm1_body<true>(As, Bs, xb, w1b + (size_t)e*H_*D_, b1all + e*H_,
                         stok, ci[CI_OFF+e], m0, min(64, count-m0), nt, heb);
    } else if (yb < 384) {
        int idx = (yb - 352)*8 + x;       // 0..255
        int mt = idx >> 3, nt = idx & 7;  // mt 0..31, nt 0..7
        gemm2_body<0>(As, Bs, heb, w2b_c + (size_t)7*D_*HP, b2all + 7*D_,
                      nullptr, SHARED_BASE, mt*64, 64, nt, out, nullptr);
    } else {
        // ---- routed W2 convert: wave per 2 rows, 448 blocks x 16 rows = 7168 rows ----
        int idx = (yb - 384)*8 + x;       // 0..447
        int lane = threadIdx.x & 63;
        int rw0 = idx*16 + (threadIdx.x >> 6)*2;
        #pragma unroll
        for (int j = 0; j < 2; j++) {
            int rw = rw0 + j;              // 0..7167
            int ec = rw >> 10, drow = rw & 1023;
            const float* src = W2 + ((size_t)ec*D_ + drow)*(size_t)H_;
            u16* dst = w2b + (size_t)rw*HP;
            #pragma unroll
            for (int h0 = 0; h0 < HP; h0 += 64) {
                int h = h0 + lane;
                float v = (h < H_) ? src[h] : 0.f;
                dst[h] = f2bf(v);
            }
        }
    }
}

// ===== k4: routed GEMM2 ONLY (XCD-pinned), atomicAdd into out =====
__global__ __launch_bounds__(512, 8) void k4_kernel(
    const int* __restrict__ ci, const int* __restrict__ stok, const float* __restrict__ sw,
    const u16* __restrict__ heb, const u16* __restrict__ w2b,
    const float* __restrict__ b2all, float* __restrict__ out)
{
    __shared__ u16 As[ASZ];
    __shared__ u16 Bs[BSZ];
    int x = blockIdx.x;
    if (x == 7) return;
    int yb = blockIdx.y;
    int e = x, mt = yb >> 3, nt = yb & 7;     // mt 0..31
    int count = ci[CI_COUNT+e];
    int m0 = mt*64;
    if (m0 >= count) return;
    gemm2_body<1>(As, Bs, heb, w2b + (size_t)e*D_*HP, b2all + e*D_,
                  sw, ci[CI_OFF+e], m0, min(64, count-m0), nt, out, stok);
}

extern "C" void kernel_launch(void* const* d_in, const int* in_sizes, int n_in,
                              void* d_out, int out_size, void* d_ws, size_t ws_size,
                              hipStream_t stream)
{
    const float* x   = (const float*)d_in[0];
    const float* Wg  = (const float*)d_in[1];
    const float* W1  = (const float*)d_in[2];
    const float* b1  = (const float*)d_in[3];
    const float* W2  = (const float*)d_in[4];
    const float* b2  = (const float*)d_in[5];
    const float* Ws1 = (const float*)d_in[6];
    const float* bs1 = (const float*)d_in[7];
    const float* Ws2 = (const float*)d_in[8];
    const float* bs2 = (const float*)d_in[9];
    float* out = (float*)d_out;
    char* ws = (char*)d_ws;

    int*   ci    = (int*)(ws + WS_CTRL);
    int*   tidx  = (int*)(ws + WS_TIDX);
    float* tw    = (float*)(ws + WS_TW);
    float* probs = (float*)(ws + WS_PROB);
    float* lse2  = (float*)(ws + WS_LSE2);
    int*   stok  = (int*)(ws + WS_STOK);
    float* sw    = (float*)(ws + WS_SW);
    float* b1all = (float*)(ws + WS_B1);
    float* b2all = (float*)(ws + WS_B2);
    u16*   xb    = (u16*)(ws + WS_XB);
    u16*   w1b   = (u16*)(ws + WS_W1B);
    u16*   w2b   = (u16*)(ws + WS_W2B);
    u16*   heb   = (u16*)(ws + WS_HEB);

    // k1: router (512) || W1 + b1 convert, 4-deep ILP (1536) — zero LDS
    prep_kernel<<<2048, 256, 0, stream>>>(x, Wg, W1, Ws1, b1, bs1,
                                          tidx, tw, probs, lse2, xb, w1b, b1all);
    // k2: finalize || shared GEMM1 (352 blk, 64-row tiles) || SHARED W2 + b2 (64)
    k2_kernel<<<417, 512, 0, stream>>>(Ws2, b2, bs2, w2b, b2all,
                                       tidx, tw, probs, lse2, ci, stok, sw, out,
                                       xb, w1b, b1all, heb);
    // k3: routed GEMM1 (XCD pinned) || shared GEMM2 (plain store) || ROUTED W2 convert
    k3_kernel<<<dim3(8, 352 + 32 + 56), 512, 0, stream>>>(ci, stok, xb, w1b, b1all, heb,
                                                          W2, w2b, w2b, b2all, out);
    // k4: routed GEMM2 only (atomicAdd) — MUST be a separate launch after sharedG2 stores
    k4_kernel<<<dim3(8, 256), 512, 0, stream>>>(ci, stok, sw, heb, w2b, b2all, out);
}